// Round 8
// baseline (86.566 us; speedup 1.0000x reference)
//
#include <hip/hip_runtime.h>

#define NROWS 256
#define ROWLEN 65536
#define TPB 1024
#define LOSS_IDX ((size_t)NROWS * (size_t)ROWLEN)

// XOR swizzle, key masked to 30: bits 1-4 spread across banks, bit 0
// preserved -> element pairs (2n, 2n+1) remain ADJACENT and 8B-aligned,
// enabling ds_read_b64/ds_write_b64 at stride-1 levels. Worst-case residual
// aliasing is 2-way (free, m136).
__device__ __forceinline__ int SW(int i) {
    return i ^ (((i >> 5) ^ (i >> 10)) & 30);
}

// Force a wave-uniform float into an SGPR (filter taps).
__device__ __forceinline__ float rfl(float x) {
    union { float f; int i; } u; u.f = x;
    u.i = __builtin_amdgcn_readfirstlane(u.i);
    return u.f;
}

__device__ __forceinline__ float sigm(float z) { return 1.0f / (1.0f + __expf(-z)); }

__device__ __forceinline__ float hthr(float v, float a, float bp, float bm) {
    return v * (sigm(a * (v - bp)) + sigm(-a * (v + bm)));
}

// Intra-wave "barrier" (deep levels run entirely in wave 0).
__device__ __forceinline__ void wave_sync() {
    __builtin_amdgcn_wave_barrier();
    __threadfence_block();
    __builtin_amdgcn_wave_barrier();
}

__device__ __forceinline__ void ldf_fwd(const float* sc, const float* rec, int lvl,
                                        float* sf, float* wv) {
    #pragma unroll
    for (int i = 0; i < 8; ++i) sf[i] = rfl(sc[lvl * 8 + i]);
    #pragma unroll
    for (int i = 0; i < 8; ++i) {
        float r = rfl(rec[lvl * 8 + 7 - i]);
        wv[i] = (i & 1) ? -r : r;            // _compute_wavelet
    }
}

__device__ __forceinline__ void ldf_rec(const float* sc, const float* rec, int lvl,
                                        float* sf, float* ws) {
    #pragma unroll
    for (int i = 0; i < 8; ++i) sf[i] = rfl(sc[lvl * 8 + i]);
    #pragma unroll
    for (int i = 0; i < 8; ++i) {
        float r = rfl(rec[lvl * 8 + 7 - i]);
        ws[i] = (i & 1) ? r : -r;            // _compute_wavelet_synthesis
    }
}

// ---------- strided in-place forward lifting level (STAGED) ----------
// approx pair n: even @ 2nS, odd @ (2n+1)S. Writes approx_{l+1}[n] -> 2nS,
// det_l[n] -> (2n+1)S. ALL loads (halo + own chunk) are issued before any
// store, so the compiler clusters the ds_reads (one latency exposure per
// phase) instead of serializing store->load per iteration.
template<int C, int S, int M, bool WAVE>
__device__ __forceinline__ void fwd_level(float* __restrict__ buf, int tid,
                                          const float* sf, const float* wv,
                                          float a, float bp, float bm, float& loss)
{
    const int c0 = tid * C;
    float ev[C + 7], od[C + 7];
    #pragma unroll
    for (int k = 0; k < 7; ++k) {                // left halo: pairs c0-7..c0-1
        int m = (c0 - 7 + k) & (M - 1);
        ev[k] = buf[SW(2 * m * S)];
        od[k] = buf[SW((2 * m + 1) * S)];
    }
    if constexpr (WAVE) wave_sync(); else __syncthreads();
    // stage own chunk: pure loads, no stores in between
    if constexpr (S == 1) {
        #pragma unroll
        for (int j = 0; j < C; ++j) {
            float2 v = *(const float2*)&buf[SW(2 * (c0 + j))];   // b64
            ev[7 + j] = v.x; od[7 + j] = v.y;
        }
    } else {
        #pragma unroll
        for (int j = 0; j < C; ++j) {
            ev[7 + j] = buf[SW(2 * (c0 + j) * S)];
            od[7 + j] = buf[SW((2 * (c0 + j) + 1) * S)];
        }
    }
    // compute + store
    #pragma unroll
    for (int j = 0; j < C; ++j) {
        float ao = 0.f, ae = 0.f;
        #pragma unroll
        for (int k = 0; k < 8; ++k) {
            ao = fmaf(wv[k], ev[j + 7 - k], ao);   // conv(even, wav)[n]
            ae = fmaf(sf[k], od[j + 7 - k], ae);   // conv(odd, scaling)[n]
        }
        const int n = c0 + j;
        float apx = od[j + 7] - ao;                // next approx
        float d = hthr(ev[j + 7] - ae, a, bp, bm); // thresholded detail
        loss += fabsf(d);
        if constexpr (S == 1) {
            *(float2*)&buf[SW(2 * n)] = make_float2(apx, d);     // b64
        } else {
            buf[SW(2 * n * S)] = apx;
            buf[SW((2 * n + 1) * S)] = d;
        }
    }
    if constexpr (WAVE) wave_sync(); else __syncthreads();
}

// ---------- strided in-place inverse lifting level (STAGED) ----------
template<int C, int S, int M, bool WAVE>
__device__ __forceinline__ void rec_level(float* __restrict__ buf, int tid,
                                          const float* sf, const float* ws)
{
    const int c0 = tid * C;
    float ap[C + 7], dt[C + 7];
    #pragma unroll
    for (int k = 0; k < 7; ++k) {                // right halo: pairs c0+C..c0+C+6
        int m = (c0 + C + k) & (M - 1);
        ap[C + k] = buf[SW(2 * m * S)];
        dt[C + k] = buf[SW((2 * m + 1) * S)];
    }
    if constexpr (WAVE) wave_sync(); else __syncthreads();
    // stage own chunk: pure loads
    if constexpr (S == 1) {
        #pragma unroll
        for (int k = 0; k < C; ++k) {
            float2 v = *(const float2*)&buf[SW(2 * (c0 + k))];   // b64
            ap[k] = v.x; dt[k] = v.y;
        }
    } else {
        #pragma unroll
        for (int k = 0; k < C; ++k) {
            ap[k] = buf[SW(2 * (c0 + k) * S)];
            dt[k] = buf[SW((2 * (c0 + k) + 1) * S)];
        }
    }
    // compute + store
    #pragma unroll
    for (int j = 0; j < C; ++j) {
        const int n = c0 + j;
        float er = 0.f, orr = 0.f;
        #pragma unroll
        for (int k = 0; k < 8; ++k) {
            er  = fmaf(sf[k], ap[j + k], er);    // corr(approx, scaling)[n]
            orr = fmaf(ws[k], dt[j + k], orr);   // corr(det, ws)[n]
        }
        er  += dt[j];                            // even_rest[n]
        orr += ap[j];                            // odd_rest[n]
        if constexpr (S == 1) {
            *(float2*)&buf[SW(2 * n)] = make_float2(er, orr);    // b64
        } else {
            buf[SW(2 * n * S)] = er;
            buf[SW((2 * n + 1) * S)] = orr;
        }
    }
    if constexpr (WAVE) wave_sync(); else __syncthreads();
}

// amdgpu_num_vgpr(128): grant the 4-waves/SIMD budget (the 128 KiB dynamic
// LDS forces 1 block/CU = 16 waves anyway). Taps live in SGPRs (rfl), det0
// in 32 VGPRs; staged levels peak ~90 floats live.
__global__ __launch_bounds__(TPB)
__attribute__((amdgpu_num_vgpr(128), amdgpu_waves_per_eu(4, 4)))
void wavelet_vcycle_kernel(
    const float* __restrict__ x, const float* __restrict__ scaling,
    const float* __restrict__ scaling_rec, const float* __restrict__ pa,
    const float* __restrict__ pbp, const float* __restrict__ pbm,
    float* __restrict__ out)
{
    extern __shared__ float buf[];               // 32768 floats = 128 KiB
    __shared__ float wb[16][8];                  // wave-boundary det0 halo
    __shared__ float lossbuf[16];
    const int tid  = threadIdx.x;
    const int lane = tid & 63;
    const int wv_id = tid >> 6;
    const int row = blockIdx.x;
    const float* xr = x + (size_t)row * ROWLEN;
    float* outr = out + (size_t)row * ROWLEN;
    const float a = rfl(pa[0]), bp = rfl(pbp[0]), bm = rfl(pbm[0]);
    float loss = 0.f;
    float sf[8], wv8[8];
    float det0[32];                              // level-0 details live here

    // ---------- forward level 0: x (global, rolling window) -> approx_1 (LDS,
    //            stride 1, paired b64 stores), det_0 -> registers. ----------
    ldf_fwd(scaling, scaling_rec, 0, sf, wv8);
    {
        const int c0 = tid * 32;                 // pair index base
        float ev[8], od[8];
        {
            const int b = 2 * c0;                // float index of pair c0
            float4 h0 = *(const float4*)(xr + ((b - 16) & 65535));
            float4 h1 = *(const float4*)(xr + ((b - 12) & 65535));
            float4 h2 = *(const float4*)(xr + ((b -  8) & 65535));
            float4 h3 = *(const float4*)(xr + ((b -  4) & 65535));
            ev[0] = h0.z; od[0] = h0.w;
            ev[1] = h1.x; od[1] = h1.y; ev[2] = h1.z; od[2] = h1.w;
            ev[3] = h2.x; od[3] = h2.y; ev[4] = h2.z; od[4] = h2.w;
            ev[5] = h3.x; od[5] = h3.y; ev[6] = h3.z; od[6] = h3.w;
        }
        float apx_e = 0.f;                       // even-j approx staging for b64
        #pragma unroll
        for (int jj = 0; jj < 16; ++jj) {        // one float4 = 2 pairs
            float4 v = *(const float4*)(xr + 2 * (c0 + 2 * jj));
            #pragma unroll
            for (int q = 0; q < 2; ++q) {
                const int j = 2 * jj + q;
                ev[7] = (q == 0) ? v.x : v.z;
                od[7] = (q == 0) ? v.y : v.w;
                float ao = 0.f, ae = 0.f;
                #pragma unroll
                for (int k = 0; k < 8; ++k) {
                    ao = fmaf(wv8[k], ev[7 - k], ao);
                    ae = fmaf(sf[k],  od[7 - k], ae);
                }
                float apx = od[7] - ao;          // approx_1[c0+j]
                if (q == 0) apx_e = apx;
                else *(float2*)&buf[SW(c0 + j - 1)] = make_float2(apx_e, apx);
                float d = hthr(ev[7] - ae, a, bp, bm);
                loss += fabsf(d);
                det0[j] = d;
                #pragma unroll
                for (int k = 0; k < 7; ++k) { ev[k] = ev[k + 1]; od[k] = od[k + 1]; }
            }
        }
    }
    if (lane == 0) {                             // stash det0[0..6] for halo
        #pragma unroll
        for (int k = 0; k < 7; ++k) wb[wv_id][k] = det0[k];
    }
    __syncthreads();

    // ---------- forward levels 1..4 (full block; strided in-place, staged) ----------
    ldf_fwd(scaling, scaling_rec, 1, sf, wv8); fwd_level<16, 1, 16384, false>(buf, tid, sf, wv8, a, bp, bm, loss);
    ldf_fwd(scaling, scaling_rec, 2, sf, wv8); fwd_level< 8, 2,  8192, false>(buf, tid, sf, wv8, a, bp, bm, loss);
    ldf_fwd(scaling, scaling_rec, 3, sf, wv8); fwd_level< 4, 4,  4096, false>(buf, tid, sf, wv8, a, bp, bm, loss);
    ldf_fwd(scaling, scaling_rec, 4, sf, wv8); fwd_level< 2, 8,  2048, false>(buf, tid, sf, wv8, a, bp, bm, loss);

    // ---------- deep levels 5..9 + threshold + inverse 9..5: single wave ----------
    if (wv_id == 0) {
        ldf_fwd(scaling, scaling_rec, 5, sf, wv8); fwd_level<16,  16, 1024, true>(buf, lane, sf, wv8, a, bp, bm, loss);
        ldf_fwd(scaling, scaling_rec, 6, sf, wv8); fwd_level< 8,  32,  512, true>(buf, lane, sf, wv8, a, bp, bm, loss);
        ldf_fwd(scaling, scaling_rec, 7, sf, wv8); fwd_level< 4,  64,  256, true>(buf, lane, sf, wv8, a, bp, bm, loss);
        ldf_fwd(scaling, scaling_rec, 8, sf, wv8); fwd_level< 2, 128,  128, true>(buf, lane, sf, wv8, a, bp, bm, loss);
        ldf_fwd(scaling, scaling_rec, 9, sf, wv8); fwd_level< 1, 256,   64, true>(buf, lane, sf, wv8, a, bp, bm, loss);

        // threshold approx_10: 64 elements at stride 512 (same-lane r/w)
        float v = buf[SW(lane * 512)];
        float f = hthr(v, a, bp, bm);
        loss += fabsf(f);
        buf[SW(lane * 512)] = f;
        wave_sync();

        ldf_rec(scaling, scaling_rec, 9, sf, wv8); rec_level< 1, 256,   64, true>(buf, lane, sf, wv8);
        ldf_rec(scaling, scaling_rec, 8, sf, wv8); rec_level< 2, 128,  128, true>(buf, lane, sf, wv8);
        ldf_rec(scaling, scaling_rec, 7, sf, wv8); rec_level< 4,  64,  256, true>(buf, lane, sf, wv8);
        ldf_rec(scaling, scaling_rec, 6, sf, wv8); rec_level< 8,  32,  512, true>(buf, lane, sf, wv8);
        ldf_rec(scaling, scaling_rec, 5, sf, wv8); rec_level<16,  16, 1024, true>(buf, lane, sf, wv8);
    }

    // ---------- reg_loss reduction (its barrier doubles as the post-deep sync) ----------
    {
        float l = loss;
        #pragma unroll
        for (int off = 32; off > 0; off >>= 1) l += __shfl_down(l, off, 64);
        if (lane == 0) lossbuf[wv_id] = l;
    }
    __syncthreads();
    if (tid == 0) {
        float s = 0.f;
        #pragma unroll
        for (int w = 0; w < 16; ++w) s += lossbuf[w];
        atomicAdd(out + LOSS_IDX, s);
    }

    // ---------- inverse levels 4..1 (full block, staged) ----------
    ldf_rec(scaling, scaling_rec, 4, sf, wv8); rec_level< 2, 8, 2048, false>(buf, tid, sf, wv8);
    ldf_rec(scaling, scaling_rec, 3, sf, wv8); rec_level< 4, 4, 4096, false>(buf, tid, sf, wv8);
    ldf_rec(scaling, scaling_rec, 2, sf, wv8); rec_level< 8, 2, 8192, false>(buf, tid, sf, wv8);
    ldf_rec(scaling, scaling_rec, 1, sf, wv8); rec_level<16, 1, 16384, false>(buf, tid, sf, wv8);

    // ---------- inverse level 0: approx_1 (LDS, read-only -> loads freely
    //            pipelined vs global stores) + det_0 (regs, shfl halo)
    //            -> out (global float4). ----------
    {
        ldf_rec(scaling, scaling_rec, 0, sf, wv8);
        float h[7];                              // neighbor thread's det0[0..6]
        #pragma unroll
        for (int k = 0; k < 7; ++k) h[k] = __shfl(det0[k], (lane + 1) & 63, 64);
        if (lane == 63) {
            #pragma unroll
            for (int k = 0; k < 7; ++k) h[k] = wb[(wv_id + 1) & 15][k];
        }
        #pragma unroll
        for (int p = 0; p < 2; ++p) {
            const int c0 = tid * 32 + p * 16;    // pair index
            float ap[8];                         // approx window [c0 .. c0+7]
            #pragma unroll
            for (int k = 0; k < 8; ++k) ap[k] = buf[SW((c0 + k) & 32767)];
            float e0 = 0.f, o0 = 0.f;
            #pragma unroll
            for (int j = 0; j < 16; ++j) {
                const int n = c0 + j;
                float er = 0.f, orr = 0.f;
                #pragma unroll
                for (int k = 0; k < 8; ++k) {
                    const int di = p * 16 + j + k;           // compile-time
                    float dv = (di < 32) ? det0[di] : h[di - 32];
                    er  = fmaf(sf[k],  ap[k], er);
                    orr = fmaf(wv8[k], dv,    orr);
                }
                const int d0i = p * 16 + j;
                float dvj = (d0i < 32) ? det0[d0i] : h[d0i - 32];
                er  += dvj;                      // even_rest[n]
                orr += ap[0];                    // odd_rest[n]
                if ((j & 1) == 0) { e0 = er; o0 = orr; }
                else *(float4*)(outr + 2 * (n - 1)) = make_float4(e0, o0, er, orr);
                if (j < 15) {
                    #pragma unroll
                    for (int k = 0; k < 7; ++k) ap[k] = ap[k + 1];
                    ap[7] = buf[SW((n + 8) & 32767)];
                }
            }
        }
    }
}

extern "C" void kernel_launch(void* const* d_in, const int* in_sizes, int n_in,
                              void* d_out, int out_size, void* d_ws, size_t ws_size,
                              hipStream_t stream) {
    const float* x           = (const float*)d_in[0];
    const float* scaling     = (const float*)d_in[1];
    const float* scaling_rec = (const float*)d_in[2];
    const float* p_alpha     = (const float*)d_in[3];
    const float* p_bp        = (const float*)d_in[4];
    const float* p_bm        = (const float*)d_in[5];
    float* out = (float*)d_out;

    // zero the loss accumulator each launch (graph-capture safe)
    hipMemsetAsync(out + LOSS_IDX, 0, sizeof(float), stream);

    wavelet_vcycle_kernel<<<dim3(NROWS), dim3(TPB), 32768 * sizeof(float), stream>>>(
        x, scaling, scaling_rec, p_alpha, p_bp, p_bm, out);
}

// Round 9
// 73.493 us; speedup vs baseline: 1.1779x; 1.1779x over previous
//
#include <hip/hip_runtime.h>

#define NROWS 256
#define ROWLEN 65536
#define TPB 1024
#define LOSS_IDX ((size_t)NROWS * (size_t)ROWLEN)

// XOR swizzle: bijective (only bits 0-4 modified). Spreads strided accesses
// across banks. Applied to EVERY access of buf[]. (R7's &31 version — the
// &30/b64 variant of R8 quadrupled conflicts.)
__device__ __forceinline__ int SW(int i) {
    return i ^ (((i >> 5) ^ (i >> 10)) & 31);
}

// Force a wave-uniform float into an SGPR (filter taps).
__device__ __forceinline__ float rfl(float x) {
    union { float f; int i; } u; u.f = x;
    u.i = __builtin_amdgcn_readfirstlane(u.i);
    return u.f;
}

// Double-sigmoid threshold with ONE fast rcp:
//   s(z1)+s(z2) = (2+e1+e2) / ((1+e1)(1+e2)),  e1=exp(-z1), e2=exp(-z2)
// replaces two full-precision divides. Exp args clamped so e1*e2 stays finite
// (clamped branch is exact in the limit: ratio -> 1/(1+e_other)).
__device__ __forceinline__ float hthr(float v, float a, float bp, float bm) {
    float e1 = __expf(fminf(-a * (v - bp), 80.f));
    float e2 = __expf(fminf( a * (v + bm), 80.f));
    float s  = e1 + e2;
    float num = 2.f + s;
    float den = fmaf(e1, e2, 1.f + s);       // 1 + e1 + e2 + e1*e2
    return v * num * __builtin_amdgcn_rcpf(den);
}

// Intra-wave "barrier" (deepest levels run entirely in wave 0).
__device__ __forceinline__ void wave_sync() {
    __builtin_amdgcn_wave_barrier();
    __threadfence_block();
    __builtin_amdgcn_wave_barrier();
}

__device__ __forceinline__ void ldf_fwd(const float* sc, const float* rec, int lvl,
                                        float* sf, float* wv) {
    #pragma unroll
    for (int i = 0; i < 8; ++i) sf[i] = rfl(sc[lvl * 8 + i]);
    #pragma unroll
    for (int i = 0; i < 8; ++i) {
        float r = rfl(rec[lvl * 8 + 7 - i]);
        wv[i] = (i & 1) ? -r : r;            // _compute_wavelet
    }
}

__device__ __forceinline__ void ldf_rec(const float* sc, const float* rec, int lvl,
                                        float* sf, float* ws) {
    #pragma unroll
    for (int i = 0; i < 8; ++i) sf[i] = rfl(sc[lvl * 8 + i]);
    #pragma unroll
    for (int i = 0; i < 8; ++i) {
        float r = rfl(rec[lvl * 8 + 7 - i]);
        ws[i] = (i & 1) ? r : -r;            // _compute_wavelet_synthesis
    }
}

// ---------- strided in-place forward lifting level (rolling window) ----------
// approx pair n: even @ 2nS, odd @ (2n+1)S. Writes approx_{l+1}[n] -> 2nS,
// det_l[n] -> (2n+1)S. GUARD: only tid*C < M threads active (barriers still
// block-wide). WAVE: single-wave mode (tid = lane), wave_sync.
template<int C, int S, int M, bool WAVE, bool GUARD>
__device__ __forceinline__ void fwd_level(float* __restrict__ buf, int tid,
                                          const float* sf, const float* wv,
                                          float a, float bp, float bm, float& loss)
{
    const bool act = !GUARD || (tid * C < M);
    const int c0 = tid * C;
    float ev[8], od[8];
    if (act) {
        #pragma unroll
        for (int k = 0; k < 7; ++k) {            // left halo: pairs c0-7..c0-1
            int m = (c0 - 7 + k) & (M - 1);
            ev[k] = buf[SW(2 * m * S)];
            od[k] = buf[SW((2 * m + 1) * S)];
        }
    }
    if constexpr (WAVE) wave_sync(); else __syncthreads();
    if (act) {
        float ne = buf[SW(2 * c0 * S)];          // 1-ahead prefetch
        float no = buf[SW((2 * c0 + 1) * S)];
        #pragma unroll
        for (int j = 0; j < C; ++j) {
            const int n = c0 + j;
            ev[7] = ne; od[7] = no;
            if (j + 1 < C) {
                ne = buf[SW(2 * (n + 1) * S)];
                no = buf[SW((2 * (n + 1) + 1) * S)];
            }
            float ao = 0.f, ae = 0.f;
            #pragma unroll
            for (int k = 0; k < 8; ++k) {
                ao = fmaf(wv[k], ev[7 - k], ao); // conv(even, wav)[n]
                ae = fmaf(sf[k], od[7 - k], ae); // conv(odd, scaling)[n]
            }
            buf[SW(2 * n * S)] = od[7] - ao;     // next approx (even slot)
            float d = hthr(ev[7] - ae, a, bp, bm);
            loss += fabsf(d);
            buf[SW((2 * n + 1) * S)] = d;        // det stays in odd slot
            #pragma unroll
            for (int k = 0; k < 7; ++k) { ev[k] = ev[k + 1]; od[k] = od[k + 1]; }
        }
    }
    if constexpr (WAVE) wave_sync(); else __syncthreads();
}

// ---------- strided in-place inverse lifting level (rolling window) ----------
template<int C, int S, int M, bool WAVE, bool GUARD>
__device__ __forceinline__ void rec_level(float* __restrict__ buf, int tid,
                                          const float* sf, const float* ws)
{
    const bool act = !GUARD || (tid * C < M);
    const int c0 = tid * C;
    float ha[7], hd[7];
    if (act) {
        #pragma unroll
        for (int k = 0; k < 7; ++k) {            // right halo: pairs c0+C..c0+C+6
            int m = (c0 + C + k) & (M - 1);
            ha[k] = buf[SW(2 * m * S)];
            hd[k] = buf[SW((2 * m + 1) * S)];
        }
    }
    if constexpr (WAVE) wave_sync(); else __syncthreads();
    if (act) {
        float ap[8], dt[8];
        #pragma unroll
        for (int k = 0; k < 8; ++k) {            // window [c0 .. c0+7]
            if (k < C) {
                ap[k] = buf[SW(2 * (c0 + k) * S)];
                dt[k] = buf[SW((2 * (c0 + k) + 1) * S)];
            } else {
                ap[k] = ha[k - C];
                dt[k] = hd[k - C];
            }
        }
        #pragma unroll
        for (int j = 0; j < C; ++j) {
            const int n = c0 + j;
            float er = 0.f, orr = 0.f;
            #pragma unroll
            for (int k = 0; k < 8; ++k) {
                er  = fmaf(sf[k], ap[k], er);    // corr(approx, scaling)[n]
                orr = fmaf(ws[k], dt[k], orr);   // corr(det, ws)[n]
            }
            er  += dt[0];                        // even_rest[n]
            orr += ap[0];                        // odd_rest[n]
            buf[SW(2 * n * S)] = er;
            buf[SW((2 * n + 1) * S)] = orr;
            if (j + 1 < C) {
                #pragma unroll
                for (int k = 0; k < 7; ++k) { ap[k] = ap[k + 1]; dt[k] = dt[k + 1]; }
                const int nn = n + 8;
                if (j + 8 < C) {
                    ap[7] = buf[SW(2 * nn * S)];
                    dt[7] = buf[SW((2 * nn + 1) * S)];
                } else {
                    ap[7] = ha[j + 8 - C];
                    dt[7] = hd[j + 8 - C];
                }
            }
        }
    }
    if constexpr (WAVE) wave_sync(); else __syncthreads();
}

__global__ __launch_bounds__(TPB)
__attribute__((amdgpu_num_vgpr(128), amdgpu_waves_per_eu(4, 4)))
void wavelet_vcycle_kernel(
    const float* __restrict__ x, const float* __restrict__ scaling,
    const float* __restrict__ scaling_rec, const float* __restrict__ pa,
    const float* __restrict__ pbp, const float* __restrict__ pbm,
    float* __restrict__ out)
{
    extern __shared__ float buf[];               // 32768 floats = 128 KiB
    __shared__ float wb[16][8];                  // wave-boundary det0 halo
    __shared__ float lossbuf[16];
    const int tid  = threadIdx.x;
    const int lane = tid & 63;
    const int wv_id = tid >> 6;
    const int row = blockIdx.x;
    const float* xr = x + (size_t)row * ROWLEN;
    float* outr = out + (size_t)row * ROWLEN;
    const float a = rfl(pa[0]), bp = rfl(pbp[0]), bm = rfl(pbm[0]);
    float loss = 0.f;
    float sf[8], wv8[8];
    float det0[32];                              // level-0 details live here

    // ---------- forward level 0: x (global, 4-deep float4 prefetch ring) ->
    //            approx_1 (LDS, stride 1), det_0 -> registers. ----------
    ldf_fwd(scaling, scaling_rec, 0, sf, wv8);
    {
        const int c0 = tid * 32;                 // pair index base
        float ev[8], od[8];
        {
            const int b = 2 * c0;                // float index of pair c0
            float4 h0 = *(const float4*)(xr + ((b - 16) & 65535));
            float4 h1 = *(const float4*)(xr + ((b - 12) & 65535));
            float4 h2 = *(const float4*)(xr + ((b -  8) & 65535));
            float4 h3 = *(const float4*)(xr + ((b -  4) & 65535));
            ev[0] = h0.z; od[0] = h0.w;
            ev[1] = h1.x; od[1] = h1.y; ev[2] = h1.z; od[2] = h1.w;
            ev[3] = h2.x; od[3] = h2.y; ev[4] = h2.z; od[4] = h2.w;
            ev[5] = h3.x; od[5] = h3.y; ev[6] = h3.z; od[6] = h3.w;
        }
        float4 x4[4];                            // 4-deep prefetch ring
        #pragma unroll
        for (int jj = 0; jj < 4; ++jj)
            x4[jj] = *(const float4*)(xr + 2 * (c0 + 2 * jj));
        #pragma unroll
        for (int jj = 0; jj < 16; ++jj) {        // one float4 = 2 pairs
            float4 v = x4[jj & 3];
            if (jj + 4 < 16)
                x4[jj & 3] = *(const float4*)(xr + 2 * (c0 + 2 * (jj + 4)));
            #pragma unroll
            for (int q = 0; q < 2; ++q) {
                const int j = 2 * jj + q;
                ev[7] = (q == 0) ? v.x : v.z;
                od[7] = (q == 0) ? v.y : v.w;
                float ao = 0.f, ae = 0.f;
                #pragma unroll
                for (int k = 0; k < 8; ++k) {
                    ao = fmaf(wv8[k], ev[7 - k], ao);
                    ae = fmaf(sf[k],  od[7 - k], ae);
                }
                buf[SW(c0 + j)] = od[7] - ao;    // approx_1[c0+j]
                float d = hthr(ev[7] - ae, a, bp, bm);
                loss += fabsf(d);
                det0[j] = d;
                #pragma unroll
                for (int k = 0; k < 7; ++k) { ev[k] = ev[k + 1]; od[k] = od[k + 1]; }
            }
        }
    }
    if (lane == 0) {                             // stash det0[0..6] for halo
        #pragma unroll
        for (int k = 0; k < 7; ++k) wb[wv_id][k] = det0[k];
    }
    __syncthreads();

    // ---------- forward levels 1..6 (full block; strided in-place) ----------
    ldf_fwd(scaling, scaling_rec, 1, sf, wv8); fwd_level<16, 1, 16384, false, false>(buf, tid, sf, wv8, a, bp, bm, loss);
    ldf_fwd(scaling, scaling_rec, 2, sf, wv8); fwd_level< 8, 2,  8192, false, false>(buf, tid, sf, wv8, a, bp, bm, loss);
    ldf_fwd(scaling, scaling_rec, 3, sf, wv8); fwd_level< 4, 4,  4096, false, false>(buf, tid, sf, wv8, a, bp, bm, loss);
    ldf_fwd(scaling, scaling_rec, 4, sf, wv8); fwd_level< 2, 8,  2048, false, false>(buf, tid, sf, wv8, a, bp, bm, loss);
    ldf_fwd(scaling, scaling_rec, 5, sf, wv8); fwd_level< 1, 16, 1024, false, false>(buf, tid, sf, wv8, a, bp, bm, loss);
    ldf_fwd(scaling, scaling_rec, 6, sf, wv8); fwd_level< 1, 32,  512, false, true >(buf, tid, sf, wv8, a, bp, bm, loss);

    // ---------- deepest levels 7..9 + threshold + inverse 9..7: single wave ----------
    if (wv_id == 0) {
        ldf_fwd(scaling, scaling_rec, 7, sf, wv8); fwd_level< 4,  64, 256, true, false>(buf, lane, sf, wv8, a, bp, bm, loss);
        ldf_fwd(scaling, scaling_rec, 8, sf, wv8); fwd_level< 2, 128, 128, true, false>(buf, lane, sf, wv8, a, bp, bm, loss);
        ldf_fwd(scaling, scaling_rec, 9, sf, wv8); fwd_level< 1, 256,  64, true, false>(buf, lane, sf, wv8, a, bp, bm, loss);

        // threshold approx_10: 64 elements at stride 512 (same-lane r/w)
        float v = buf[SW(lane * 512)];
        float f = hthr(v, a, bp, bm);
        loss += fabsf(f);
        buf[SW(lane * 512)] = f;
        wave_sync();

        ldf_rec(scaling, scaling_rec, 9, sf, wv8); rec_level< 1, 256,  64, true, false>(buf, lane, sf, wv8);
        ldf_rec(scaling, scaling_rec, 8, sf, wv8); rec_level< 2, 128, 128, true, false>(buf, lane, sf, wv8);
        ldf_rec(scaling, scaling_rec, 7, sf, wv8); rec_level< 4,  64, 256, true, false>(buf, lane, sf, wv8);
    }

    // ---------- reg_loss reduction (its barrier doubles as the post-deep sync) ----------
    {
        float l = loss;
        #pragma unroll
        for (int off = 32; off > 0; off >>= 1) l += __shfl_down(l, off, 64);
        if (lane == 0) lossbuf[wv_id] = l;
    }
    __syncthreads();
    if (tid == 0) {
        float s = 0.f;
        #pragma unroll
        for (int w = 0; w < 16; ++w) s += lossbuf[w];
        atomicAdd(out + LOSS_IDX, s);
    }

    // ---------- inverse levels 6..1 (full block) ----------
    ldf_rec(scaling, scaling_rec, 6, sf, wv8); rec_level< 1, 32,  512, false, true >(buf, tid, sf, wv8);
    ldf_rec(scaling, scaling_rec, 5, sf, wv8); rec_level< 1, 16, 1024, false, false>(buf, tid, sf, wv8);
    ldf_rec(scaling, scaling_rec, 4, sf, wv8); rec_level< 2, 8,  2048, false, false>(buf, tid, sf, wv8);
    ldf_rec(scaling, scaling_rec, 3, sf, wv8); rec_level< 4, 4,  4096, false, false>(buf, tid, sf, wv8);
    ldf_rec(scaling, scaling_rec, 2, sf, wv8); rec_level< 8, 2,  8192, false, false>(buf, tid, sf, wv8);
    ldf_rec(scaling, scaling_rec, 1, sf, wv8); rec_level<16, 1, 16384, false, false>(buf, tid, sf, wv8);

    // ---------- inverse level 0: approx_1 (LDS, read-only -> no barrier) +
    //            det_0 (regs, shfl halo) -> out (global float4). ----------
    {
        ldf_rec(scaling, scaling_rec, 0, sf, wv8);
        float h[7];                              // neighbor thread's det0[0..6]
        #pragma unroll
        for (int k = 0; k < 7; ++k) h[k] = __shfl(det0[k], (lane + 1) & 63, 64);
        if (lane == 63) {
            #pragma unroll
            for (int k = 0; k < 7; ++k) h[k] = wb[(wv_id + 1) & 15][k];
        }
        #pragma unroll
        for (int p = 0; p < 2; ++p) {
            const int c0 = tid * 32 + p * 16;    // pair index
            float ap[8];                         // approx window [c0 .. c0+7]
            #pragma unroll
            for (int k = 0; k < 8; ++k) ap[k] = buf[SW((c0 + k) & 32767)];
            float e0 = 0.f, o0 = 0.f;
            #pragma unroll
            for (int j = 0; j < 16; ++j) {
                const int n = c0 + j;
                float er = 0.f, orr = 0.f;
                #pragma unroll
                for (int k = 0; k < 8; ++k) {
                    const int di = p * 16 + j + k;           // compile-time
                    float dv = (di < 32) ? det0[di] : h[di - 32];
                    er  = fmaf(sf[k],  ap[k], er);
                    orr = fmaf(wv8[k], dv,    orr);
                }
                const int d0i = p * 16 + j;
                float dvj = (d0i < 32) ? det0[d0i] : h[d0i - 32];
                er  += dvj;                      // even_rest[n]
                orr += ap[0];                    // odd_rest[n]
                if ((j & 1) == 0) { e0 = er; o0 = orr; }
                else *(float4*)(outr + 2 * (n - 1)) = make_float4(e0, o0, er, orr);
                if (j < 15) {
                    #pragma unroll
                    for (int k = 0; k < 7; ++k) ap[k] = ap[k + 1];
                    ap[7] = buf[SW((n + 8) & 32767)];
                }
            }
        }
    }
}

extern "C" void kernel_launch(void* const* d_in, const int* in_sizes, int n_in,
                              void* d_out, int out_size, void* d_ws, size_t ws_size,
                              hipStream_t stream) {
    const float* x           = (const float*)d_in[0];
    const float* scaling     = (const float*)d_in[1];
    const float* scaling_rec = (const float*)d_in[2];
    const float* p_alpha     = (const float*)d_in[3];
    const float* p_bp        = (const float*)d_in[4];
    const float* p_bm        = (const float*)d_in[5];
    float* out = (float*)d_out;

    // zero the loss accumulator each launch (graph-capture safe)
    hipMemsetAsync(out + LOSS_IDX, 0, sizeof(float), stream);

    wavelet_vcycle_kernel<<<dim3(NROWS), dim3(TPB), 32768 * sizeof(float), stream>>>(
        x, scaling, scaling_rec, p_alpha, p_bp, p_bm, out);
}